// Round 8
// baseline (313.839 us; speedup 1.0000x reference)
//
#include <hip/hip_runtime.h>
#include <cstdint>

// NewsEncoder: B=8192, L=64, D=256, H=8, DH=32, VOCAB=50000.
// R8: main_kernel v2 — no x LDS staging (MFMA A-frags direct from ebf),
// redundant per-wave coef (no single-wave phase), y-phase split by HEAD
// (no cross-wave reduce). LDS 40448 -> 4608 B, 6 barriers -> 3.
// Rest of pipeline unchanged from R7.
// Workspace (ushort units): mbf[2048] | xbf[8192*256] | tkn[2048*256] |
//   cbf[8192*2048] | ebf[50000*256] (aliased by cbar f32)  => ~61.4 MB

using f32x4  = __attribute__((ext_vector_type(4))) float;
using bf16x8 = __attribute__((ext_vector_type(8))) short;

__device__ __forceinline__ unsigned int pack2bf(float a, float b) {
  unsigned int ua = __builtin_bit_cast(unsigned int, a);
  unsigned int ub = __builtin_bit_cast(unsigned int, b);
  ua = (ua + 0x7fffu + ((ua >> 16) & 1u)) >> 16;   // RTNE to bf16
  ub = (ub + 0x7fffu + ((ub >> 16) & 1u)) >> 16;
  return ua | (ub << 16);
}
__device__ __forceinline__ unsigned short bf1(float a) {
  unsigned int ua = __builtin_bit_cast(unsigned int, a);
  ua = (ua + 0x7fffu + ((ua >> 16) & 1u)) >> 16;
  return (unsigned short)ua;
}
__device__ __forceinline__ float ubf(unsigned int u) {
  return __builtin_bit_cast(float, u << 16);
}

// ---- prep: WOd[d] = WO[d,:]@dw;  m[h][d] = sum_j WV[d][h*32+j]*WOd[h*32+j] (bf16 out)
__global__ __launch_bounds__(256) void prep_kernel(const float* __restrict__ WV,
                                                   const float* __restrict__ WO,
                                                   const float* __restrict__ dw,
                                                   unsigned short* __restrict__ mbf) {
  __shared__ float wod[256];
  const int t = threadIdx.x;
  float acc = 0.f;
  for (int e = 0; e < 256; e += 4) {
    const float4 w4 = *(const float4*)(WO + (size_t)t * 256 + e);
    const float4 d4 = *(const float4*)(dw + e);
    acc += w4.x * d4.x + w4.y * d4.y + w4.z * d4.z + w4.w * d4.w;
  }
  wod[t] = acc;
  __syncthreads();
  for (int h = 0; h < 8; ++h) {
    float a = 0.f;
    for (int j = 0; j < 32; j += 4) {
      const float4 w4 = *(const float4*)(WV + (size_t)t * 256 + h * 32 + j);
      a += w4.x * wod[h*32+j] + w4.y * wod[h*32+j+1] + w4.z * wod[h*32+j+2] + w4.w * wod[h*32+j+3];
    }
    const float o = __shfl_xor(a, 1);
    if (!(t & 1)) ((unsigned int*)mbf)[h * 128 + (t >> 1)] = pack2bf(a, o);
  }
}

// ---- prep_T: Tkn[n=h*256+e][d] = sum_j WQ[d][hj]*WK[e][hj] + WK[d][hj]*WQ[e][hj] (bf16)
__global__ __launch_bounds__(256) void prep_T(const float* __restrict__ WQ,
                                              const float* __restrict__ WK,
                                              unsigned short* __restrict__ tkn) {
  __shared__ float ek[8][32], eq[8][32];
  const int t = threadIdx.x;
  const int n0 = blockIdx.x * 8;          // 8 n-rows per block, same head
  const int h  = n0 >> 8;
  {
    const int ei = t >> 5, j = t & 31;
    const int e = (n0 & 255) + ei;
    ek[ei][j] = WK[(size_t)e * 256 + h * 32 + j];
    eq[ei][j] = WQ[(size_t)e * 256 + h * 32 + j];
  }
  __syncthreads();
  float wqd[32], wkd[32];
#pragma unroll
  for (int j = 0; j < 32; j += 4) {
    *(float4*)(wqd + j) = *(const float4*)(WQ + (size_t)t * 256 + h * 32 + j);
    *(float4*)(wkd + j) = *(const float4*)(WK + (size_t)t * 256 + h * 32 + j);
  }
#pragma unroll
  for (int ei = 0; ei < 8; ++ei) {
    float a = 0.f;
#pragma unroll
    for (int j = 0; j < 32; ++j) a += wqd[j] * ek[ei][j] + wkd[j] * eq[ei][j];
    const float o = __shfl_xor(a, 1);
    if (!(t & 1)) ((unsigned int*)tkn)[(size_t)(n0 + ei) * 128 + (t >> 1)] = pack2bf(a, o);
  }
}

// ---- K0: convert emb (f32) -> ebf (bf16)
__global__ __launch_bounds__(256) void ebf_kernel(const float4* __restrict__ emb4,
                                                  uint2* __restrict__ out2, int n) {
  for (int i = blockIdx.x * 256 + threadIdx.x; i < n; i += gridDim.x * 256) {
    const float4 v = emb4[i];
    uint2 pk;
    pk.x = pack2bf(v.x, v.y);
    pk.y = pack2bf(v.z, v.w);
    out2[i] = pk;
  }
}

// ---- K1: xbar[b][d] = mean_l ebf[tok[b][l]][d]  (bf16 in/out, f32 accum)
__global__ __launch_bounds__(256) void xbar_kernel(const int* __restrict__ tokens,
                                                   const unsigned short* __restrict__ ebf,
                                                   unsigned short* __restrict__ xbf) {
  __shared__ int tok[64];
  __shared__ float part[4][64][4];          // 4 KB
  const int b = blockIdx.x, t = threadIdx.x;
  if (t < 64) tok[t] = tokens[b * 64 + t];
  __syncthreads();
  const int cp = t & 63, rg = t >> 6;       // col-quad, row-group
  const uint2* e2 = (const uint2*)ebf;
  float s0 = 0.f, s1 = 0.f, s2 = 0.f, s3 = 0.f;
#pragma unroll
  for (int ri = 0; ri < 16; ++ri) {
    const uint2 u = e2[(size_t)tok[rg * 16 + ri] * 64 + cp];
    s0 += ubf(u.x & 0xffffu); s1 += ubf(u.x >> 16);
    s2 += ubf(u.y & 0xffffu); s3 += ubf(u.y >> 16);
  }
  *(float4*)part[rg][cp] = make_float4(s0, s1, s2, s3);
  __syncthreads();
  if (t < 64) {
    const float4 p0 = *(const float4*)part[0][t];
    const float4 p1 = *(const float4*)part[1][t];
    const float4 p2 = *(const float4*)part[2][t];
    const float4 p3 = *(const float4*)part[3][t];
    const float a0 = (p0.x + p1.x + p2.x + p3.x) * (1.f / 64.f);
    const float a1 = (p0.y + p1.y + p2.y + p3.y) * (1.f / 64.f);
    const float a2 = (p0.z + p1.z + p2.z + p3.z) * (1.f / 64.f);
    const float a3 = (p0.w + p1.w + p2.w + p3.w) * (1.f / 64.f);
    uint2 pk;
    pk.x = pack2bf(a0, a1);
    pk.y = pack2bf(a2, a3);
    *(uint2*)((unsigned int*)xbf + (size_t)b * 128 + 2 * t) = pk;
  }
}

// ---- K2: cbf[b][n] = sum_d xbf[b][d] * tkn[n][d]  (bf16 MFMA GEMM)
__global__ __launch_bounds__(256) void cgemm(const unsigned short* __restrict__ xbf,
                                             const unsigned short* __restrict__ tkn,
                                             unsigned short* __restrict__ cbf) {
  __shared__ unsigned short As[64 * 264];   // 33,792 B
  const int t = threadIdx.x;
  const int m0 = blockIdx.x * 64, n0 = blockIdx.y * 64;
#pragma unroll
  for (int it = 0; it < 8; ++it) {
    const int idx = it * 256 + t;
    const int row = idx >> 5, c = idx & 31;
    const uint4 v = *(const uint4*)(xbf + (size_t)(m0 + row) * 256 + c * 8);
    *(uint4*)(As + row * 264 + c * 8) = v;
  }
  __syncthreads();
  const int wv = t >> 6, l = t & 63;
  const int g = l >> 4, r = l & 15;
#pragma unroll
  for (int nt = 0; nt < 4; ++nt) {
    const int n = n0 + nt * 16 + r;
    f32x4 acc = {0.f, 0.f, 0.f, 0.f};
#pragma unroll
    for (int kk = 0; kk < 8; ++kk) {
      const bf16x8 a  = *(const bf16x8*)(As + (16 * wv + r) * 264 + kk * 32 + g * 8);
      const bf16x8 bb = *(const bf16x8*)(tkn + (size_t)n * 256 + kk * 32 + g * 8);
      acc = __builtin_amdgcn_mfma_f32_16x16x32_bf16(a, bb, acc, 0, 0, 0);
    }
#pragma unroll
    for (int i = 0; i < 4; ++i)
      cbf[(size_t)(m0 + 16 * wv + g * 4 + i) * 2048 + n] = bf1(acc[i]);
  }
}

// ---- K3: main v2 — per-sample; tiny LDS, 3 barriers, all-wave phases.
__global__ __launch_bounds__(256) void main_kernel(const int* __restrict__ tokens,
                                                   const unsigned short* __restrict__ ebf,
                                                   const unsigned short* __restrict__ mbf,
                                                   const float* __restrict__ dense_b,
                                                   unsigned short* __restrict__ cbf) {
  __shared__ int tok[64];                   // 256 B
  __shared__ float wslds[64 * 17];          // 4,352 B: cols 0-7 w->p, 8-15 s
  const int t = threadIdx.x;
  const int b = blockIdx.x;
  const int wv = t >> 6, l = t & 63;
  const int g = l >> 4, r = l & 15;
  if (t < 64) tok[t] = tokens[b * 64 + t];
  __syncthreads();                          // barrier 1: tok visible
  // Phase 1: [W|S] = X[64,256] @ [c|m]^T; A-frags DIRECT from ebf (gather)
  {
    const unsigned short* arow = ebf + (size_t)tok[16 * wv + r] * 256;
    const unsigned short* brow = (r < 8) ? (cbf + (size_t)b * 2048 + r * 256)
                                         : (mbf + (size_t)(r - 8) * 256);
    f32x4 acc = {0.f, 0.f, 0.f, 0.f};
#pragma unroll
    for (int kk = 0; kk < 8; ++kk) {
      const bf16x8 a  = *(const bf16x8*)(arow + kk * 32 + g * 8);
      const bf16x8 bb = *(const bf16x8*)(brow + kk * 32 + g * 8);
      acc = __builtin_amdgcn_mfma_f32_16x16x32_bf16(a, bb, acc, 0, 0, 0);
    }
#pragma unroll
    for (int i = 0; i < 4; ++i)
      wslds[(16 * wv + g * 4 + i) * 17 + r] = acc[i];
  }
  __syncthreads();                          // barrier 2: logits complete
  // Phase 2: per-head softmax over seq (wave w handles heads 2w, 2w+1)
  {
#pragma unroll
    for (int hh = 0; hh < 2; ++hh) {
      const int h = 2 * wv + hh;
      const float v = wslds[l * 17 + h];
      float mx = v;
#pragma unroll
      for (int sft = 32; sft; sft >>= 1) mx = fmaxf(mx, __shfl_xor(mx, sft));
      const float e = expf(v - mx);
      float sm = e;
#pragma unroll
      for (int sft = 32; sft; sft >>= 1) sm += __shfl_xor(sm, sft);
      wslds[l * 17 + h] = e / sm;
    }
  }
  __syncthreads();                          // barrier 3: p complete
  // Phase 3 (every wave, redundant): scores softmax -> coef in registers
  float cc0, cc1;
  {
    float p[8], sv[8];
#pragma unroll
    for (int h = 0; h < 8; ++h) { p[h] = wslds[l*17 + h]; sv[h] = wslds[l*17 + 8 + h]; }
    float sc = dense_b[0];
#pragma unroll
    for (int h = 0; h < 8; ++h) sc += p[h] * sv[h];
    float mx = sc;
#pragma unroll
    for (int sft = 32; sft; sft >>= 1) mx = fmaxf(mx, __shfl_xor(mx, sft));
    const float e = expf(sc - mx);
    float sm = e;
#pragma unroll
    for (int sft = 32; sft; sft >>= 1) sm += __shfl_xor(sm, sft);
    const float attn = e / sm;
    float co[8];
#pragma unroll
    for (int h = 0; h < 8; ++h) co[h] = attn * p[h];
    if      (wv == 0) { cc0 = co[0]; cc1 = co[1]; }
    else if (wv == 1) { cc0 = co[2]; cc1 = co[3]; }
    else if (wv == 2) { cc0 = co[4]; cc1 = co[5]; }
    else              { cc0 = co[6]; cc1 = co[7]; }
  }
  // Phase 4: y by head — wave w owns h=2w,2w+1; lane owns 4 d-cols; x from L2
  {
    float y0[4] = {}, y1[4] = {};
#pragma unroll
    for (int ll = 0; ll < 64; ++ll) {
      const uint2 xv = *(const uint2*)(ebf + (size_t)tok[ll] * 256 + l * 4);
      const float c0 = __shfl(cc0, ll);
      const float c1 = __shfl(cc1, ll);
      const float x0 = ubf(xv.x & 0xffffu);
      const float x1 = ubf(xv.x >> 16);
      const float x2 = ubf(xv.y & 0xffffu);
      const float x3 = ubf(xv.y >> 16);
      y0[0] += c0 * x0; y0[1] += c0 * x1; y0[2] += c0 * x2; y0[3] += c0 * x3;
      y1[0] += c1 * x0; y1[1] += c1 * x1; y1[2] += c1 * x2; y1[3] += c1 * x3;
    }
    uint2 pk0, pk1;
    pk0.x = pack2bf(y0[0], y0[1]); pk0.y = pack2bf(y0[2], y0[3]);
    pk1.x = pack2bf(y1[0], y1[1]); pk1.y = pack2bf(y1[2], y1[3]);
    *(uint2*)(cbf + (size_t)b * 2048 + (2 * wv) * 256 + l * 4)     = pk0;
    *(uint2*)(cbf + (size_t)b * 2048 + (2 * wv + 1) * 256 + l * 4) = pk1;
  }
}

// ---- generic tiled GEMM: C = A@B, row-major, grid.z strides (A optionally bf16)
template <bool A_BF16>
__global__ __launch_bounds__(256) void gemm_t(const void* __restrict__ Av,
                                              const float* __restrict__ Bm,
                                              float* __restrict__ C,
                                              int N, int K, int lda, int ldb, int ldc,
                                              long aZ, long bZ, long cZ) {
  __shared__ float As[64 * 20];
  __shared__ float Bs[16 * 68];
  const int t = threadIdx.x;
  const int bm = blockIdx.x * 64, bn = blockIdx.y * 64;
  Bm += (long)blockIdx.z * bZ;
  C  += (long)blockIdx.z * cZ;
  const int ty = t >> 4, tx = t & 15;
  const int lr = t >> 2, lj = (t & 3) * 4;
  const int lk = t >> 4, ln = (t & 15) * 4;
  float acc[4][4] = {};
  for (int k0 = 0; k0 < K; k0 += 16) {
    float4 a4;
    if constexpr (A_BF16) {
      const unsigned short* A = (const unsigned short*)Av + (long)blockIdx.z * aZ;
      const uint2 au = *(const uint2*)(A + (size_t)(bm + lr) * lda + k0 + lj);
      a4 = make_float4(ubf(au.x & 0xffffu), ubf(au.x >> 16),
                       ubf(au.y & 0xffffu), ubf(au.y >> 16));
    } else {
      const float* A = (const float*)Av + (long)blockIdx.z * aZ;
      a4 = *(const float4*)(A + (size_t)(bm + lr) * lda + k0 + lj);
    }
    float4 b4 = make_float4(0.f, 0.f, 0.f, 0.f);
    if (bn + ln < N) b4 = *(const float4*)(Bm + (size_t)(k0 + lk) * ldb + bn + ln);
    __syncthreads();
    *(float4*)(As + lr * 20 + lj) = a4;
    *(float4*)(Bs + lk * 68 + ln) = b4;
    __syncthreads();
#pragma unroll
    for (int k = 0; k < 16; ++k) {
      const float a0 = As[(4*ty+0)*20 + k];
      const float a1 = As[(4*ty+1)*20 + k];
      const float a2 = As[(4*ty+2)*20 + k];
      const float a3 = As[(4*ty+3)*20 + k];
      const float4 bb = *(const float4*)(Bs + k * 68 + 4 * tx);
      acc[0][0]+=a0*bb.x; acc[0][1]+=a0*bb.y; acc[0][2]+=a0*bb.z; acc[0][3]+=a0*bb.w;
      acc[1][0]+=a1*bb.x; acc[1][1]+=a1*bb.y; acc[1][2]+=a1*bb.z; acc[1][3]+=a1*bb.w;
      acc[2][0]+=a2*bb.x; acc[2][1]+=a2*bb.y; acc[2][2]+=a2*bb.z; acc[2][3]+=a2*bb.w;
      acc[3][0]+=a3*bb.x; acc[3][1]+=a3*bb.y; acc[3][2]+=a3*bb.z; acc[3][3]+=a3*bb.w;
    }
  }
  if (bn + 4 * tx < N) {
#pragma unroll
    for (int i = 0; i < 4; ++i) {
      *(float4*)(C + (size_t)(bm + 4*ty + i) * ldc + bn + 4*tx) =
          make_float4(acc[i][0], acc[i][1], acc[i][2], acc[i][3]);
    }
  }
}

extern "C" void kernel_launch(void* const* d_in, const int* in_sizes, int n_in,
                              void* d_out, int out_size, void* d_ws, size_t ws_size,
                              hipStream_t stream) {
  const int*   tokens = (const int*)d_in[0];
  const float* emb    = (const float*)d_in[1];
  const float* WQ     = (const float*)d_in[2];
  const float* WK     = (const float*)d_in[3];
  const float* WV     = (const float*)d_in[4];
  const float* WO     = (const float*)d_in[5];
  const float* dw     = (const float*)d_in[6];
  const float* db     = (const float*)d_in[7];
  float* out = (float*)d_out;

  // ushort-unit layout
  unsigned short* base = (unsigned short*)d_ws;
  unsigned short* mbf  = base;                           // 2048
  unsigned short* xbf  = base + 2048;                    // 8192*256   (4 MB)
  unsigned short* tkn  = xbf + (size_t)8192 * 256;       // 2048*256   (1 MB)
  unsigned short* cbf  = tkn + (size_t)2048 * 256;       // 8192*2048  (32 MB)
  unsigned short* ebf  = cbf + (size_t)8192 * 2048;      // 50000*256  (25.6 MB)
  float* cbar = (float*)ebf;                             // aliases ebf (dead after main)

  const size_t need_bytes = (size_t)(2048 + 8192*256 + 2048*256 + 8192*2048
                                     + 50000*256) * 2;
  if (ws_size < need_bytes) return;  // deterministic no-op guard

  prep_kernel<<<dim3(1), dim3(256), 0, stream>>>(WV, WO, dw, mbf);
  prep_T<<<dim3(256), dim3(256), 0, stream>>>(WQ, WK, tkn);
  // emb f32 -> ebf bf16 (50000*256)
  ebf_kernel<<<dim3(2048), dim3(256), 0, stream>>>((const float4*)emb, (uint2*)ebf,
                                                   50000 * 64);
  xbar_kernel<<<dim3(8192), dim3(256), 0, stream>>>(tokens, ebf, xbf);
  // c[b][n] for all b,n in one MFMA GEMM
  cgemm<<<dim3(128, 32), dim3(256), 0, stream>>>(xbf, tkn, cbf);
  // main per-sample: logits, softmaxes, y (overwrites c, bf16)
  main_kernel<<<dim3(8192), dim3(256), 0, stream>>>(tokens, ebf, mbf, db, cbf);
  // cbar[b][h*32+n] = sum_e y[b][h][e] * WV[e][h*32+n]   (A = bf16 y)
  gemm_t<true><<<dim3(128, 1, 8), dim3(256), 0, stream>>>(cbf, WV, cbar, 32, 256, 2048, 256, 256, 256l, 32l, 32l);
  // out = cbar @ WO
  gemm_t<false><<<dim3(128, 4, 1), dim3(256), 0, stream>>>(cbar, WO, out, 256, 256, 256, 256, 256, 0l, 0l, 0l);
}

// Round 10
// 283.611 us; speedup vs baseline: 1.1066x; 1.1066x over previous
//
#include <hip/hip_runtime.h>
#include <cstdint>

// NewsEncoder: B=8192, L=64, D=256, H=8, DH=32, VOCAB=50000.
// R10 == R9 (R9 never ran; infra flake): main_kernel v3 = R7 memory structure
// + R8 control structure. x staged in LDS ONCE (deep-pipelined uint4 loads);
// MFMA A from LDS; redundant per-wave coef (no single-wave phase); per-head y
// phase reads x from LDS (no 32KB partials round-trip, no global re-read).
// 3 barriers. LDS 38,144 B -> 4 blocks/CU. Rest of pipeline unchanged.
// Workspace (ushort units): mbf[2048] | xbf[8192*256] | tkn[2048*256] |
//   cbf[8192*2048] | ebf[50000*256] (aliased by cbar f32)  => ~61.4 MB

using f32x4  = __attribute__((ext_vector_type(4))) float;
using bf16x8 = __attribute__((ext_vector_type(8))) short;

__device__ __forceinline__ unsigned int pack2bf(float a, float b) {
  unsigned int ua = __builtin_bit_cast(unsigned int, a);
  unsigned int ub = __builtin_bit_cast(unsigned int, b);
  ua = (ua + 0x7fffu + ((ua >> 16) & 1u)) >> 16;   // RTNE to bf16
  ub = (ub + 0x7fffu + ((ub >> 16) & 1u)) >> 16;
  return ua | (ub << 16);
}
__device__ __forceinline__ unsigned short bf1(float a) {
  unsigned int ua = __builtin_bit_cast(unsigned int, a);
  ua = (ua + 0x7fffu + ((ua >> 16) & 1u)) >> 16;
  return (unsigned short)ua;
}
__device__ __forceinline__ float ubf(unsigned int u) {
  return __builtin_bit_cast(float, u << 16);
}

// ---- prep: WOd[d] = WO[d,:]@dw;  m[h][d] = sum_j WV[d][h*32+j]*WOd[h*32+j] (bf16 out)
__global__ __launch_bounds__(256) void prep_kernel(const float* __restrict__ WV,
                                                   const float* __restrict__ WO,
                                                   const float* __restrict__ dw,
                                                   unsigned short* __restrict__ mbf) {
  __shared__ float wod[256];
  const int t = threadIdx.x;
  float acc = 0.f;
  for (int e = 0; e < 256; e += 4) {
    const float4 w4 = *(const float4*)(WO + (size_t)t * 256 + e);
    const float4 d4 = *(const float4*)(dw + e);
    acc += w4.x * d4.x + w4.y * d4.y + w4.z * d4.z + w4.w * d4.w;
  }
  wod[t] = acc;
  __syncthreads();
  for (int h = 0; h < 8; ++h) {
    float a = 0.f;
    for (int j = 0; j < 32; j += 4) {
      const float4 w4 = *(const float4*)(WV + (size_t)t * 256 + h * 32 + j);
      a += w4.x * wod[h*32+j] + w4.y * wod[h*32+j+1] + w4.z * wod[h*32+j+2] + w4.w * wod[h*32+j+3];
    }
    const float o = __shfl_xor(a, 1);
    if (!(t & 1)) ((unsigned int*)mbf)[h * 128 + (t >> 1)] = pack2bf(a, o);
  }
}

// ---- prep_T: Tkn[n=h*256+e][d] = sum_j WQ[d][hj]*WK[e][hj] + WK[d][hj]*WQ[e][hj] (bf16)
__global__ __launch_bounds__(256) void prep_T(const float* __restrict__ WQ,
                                              const float* __restrict__ WK,
                                              unsigned short* __restrict__ tkn) {
  __shared__ float ek[8][32], eq[8][32];
  const int t = threadIdx.x;
  const int n0 = blockIdx.x * 8;          // 8 n-rows per block, same head
  const int h  = n0 >> 8;
  {
    const int ei = t >> 5, j = t & 31;
    const int e = (n0 & 255) + ei;
    ek[ei][j] = WK[(size_t)e * 256 + h * 32 + j];
    eq[ei][j] = WQ[(size_t)e * 256 + h * 32 + j];
  }
  __syncthreads();
  float wqd[32], wkd[32];
#pragma unroll
  for (int j = 0; j < 32; j += 4) {
    *(float4*)(wqd + j) = *(const float4*)(WQ + (size_t)t * 256 + h * 32 + j);
    *(float4*)(wkd + j) = *(const float4*)(WK + (size_t)t * 256 + h * 32 + j);
  }
#pragma unroll
  for (int ei = 0; ei < 8; ++ei) {
    float a = 0.f;
#pragma unroll
    for (int j = 0; j < 32; ++j) a += wqd[j] * ek[ei][j] + wkd[j] * eq[ei][j];
    const float o = __shfl_xor(a, 1);
    if (!(t & 1)) ((unsigned int*)tkn)[(size_t)(n0 + ei) * 128 + (t >> 1)] = pack2bf(a, o);
  }
}

// ---- K0: convert emb (f32) -> ebf (bf16)
__global__ __launch_bounds__(256) void ebf_kernel(const float4* __restrict__ emb4,
                                                  uint2* __restrict__ out2, int n) {
  for (int i = blockIdx.x * 256 + threadIdx.x; i < n; i += gridDim.x * 256) {
    const float4 v = emb4[i];
    uint2 pk;
    pk.x = pack2bf(v.x, v.y);
    pk.y = pack2bf(v.z, v.w);
    out2[i] = pk;
  }
}

// ---- K1: xbar[b][d] = mean_l ebf[tok[b][l]][d]  (bf16 in/out, f32 accum)
__global__ __launch_bounds__(256) void xbar_kernel(const int* __restrict__ tokens,
                                                   const unsigned short* __restrict__ ebf,
                                                   unsigned short* __restrict__ xbf) {
  __shared__ int tok[64];
  __shared__ float part[4][64][4];          // 4 KB
  const int b = blockIdx.x, t = threadIdx.x;
  if (t < 64) tok[t] = tokens[b * 64 + t];
  __syncthreads();
  const int cp = t & 63, rg = t >> 6;       // col-quad, row-group
  const uint2* e2 = (const uint2*)ebf;
  float s0 = 0.f, s1 = 0.f, s2 = 0.f, s3 = 0.f;
#pragma unroll
  for (int ri = 0; ri < 16; ++ri) {
    const uint2 u = e2[(size_t)tok[rg * 16 + ri] * 64 + cp];
    s0 += ubf(u.x & 0xffffu); s1 += ubf(u.x >> 16);
    s2 += ubf(u.y & 0xffffu); s3 += ubf(u.y >> 16);
  }
  *(float4*)part[rg][cp] = make_float4(s0, s1, s2, s3);
  __syncthreads();
  if (t < 64) {
    const float4 p0 = *(const float4*)part[0][t];
    const float4 p1 = *(const float4*)part[1][t];
    const float4 p2 = *(const float4*)part[2][t];
    const float4 p3 = *(const float4*)part[3][t];
    const float a0 = (p0.x + p1.x + p2.x + p3.x) * (1.f / 64.f);
    const float a1 = (p0.y + p1.y + p2.y + p3.y) * (1.f / 64.f);
    const float a2 = (p0.z + p1.z + p2.z + p3.z) * (1.f / 64.f);
    const float a3 = (p0.w + p1.w + p2.w + p3.w) * (1.f / 64.f);
    uint2 pk;
    pk.x = pack2bf(a0, a1);
    pk.y = pack2bf(a2, a3);
    *(uint2*)((unsigned int*)xbf + (size_t)b * 128 + 2 * t) = pk;
  }
}

// ---- K2: cbf[b][n] = sum_d xbf[b][d] * tkn[n][d]  (bf16 MFMA GEMM)
__global__ __launch_bounds__(256) void cgemm(const unsigned short* __restrict__ xbf,
                                             const unsigned short* __restrict__ tkn,
                                             unsigned short* __restrict__ cbf) {
  __shared__ unsigned short As[64 * 264];   // 33,792 B
  const int t = threadIdx.x;
  const int m0 = blockIdx.x * 64, n0 = blockIdx.y * 64;
#pragma unroll
  for (int it = 0; it < 8; ++it) {
    const int idx = it * 256 + t;
    const int row = idx >> 5, c = idx & 31;
    const uint4 v = *(const uint4*)(xbf + (size_t)(m0 + row) * 256 + c * 8);
    *(uint4*)(As + row * 264 + c * 8) = v;
  }
  __syncthreads();
  const int wv = t >> 6, l = t & 63;
  const int g = l >> 4, r = l & 15;
#pragma unroll
  for (int nt = 0; nt < 4; ++nt) {
    const int n = n0 + nt * 16 + r;
    f32x4 acc = {0.f, 0.f, 0.f, 0.f};
#pragma unroll
    for (int kk = 0; kk < 8; ++kk) {
      const bf16x8 a  = *(const bf16x8*)(As + (16 * wv + r) * 264 + kk * 32 + g * 8);
      const bf16x8 bb = *(const bf16x8*)(tkn + (size_t)n * 256 + kk * 32 + g * 8);
      acc = __builtin_amdgcn_mfma_f32_16x16x32_bf16(a, bb, acc, 0, 0, 0);
    }
#pragma unroll
    for (int i = 0; i < 4; ++i)
      cbf[(size_t)(m0 + 16 * wv + g * 4 + i) * 2048 + n] = bf1(acc[i]);
  }
}

// ---- K3: main v3 — x staged once in LDS; 3 barriers; all-wave phases;
//          per-head y phase reads x from LDS.
__global__ __launch_bounds__(256) void main_kernel(const int* __restrict__ tokens,
                                                   const unsigned short* __restrict__ ebf,
                                                   const unsigned short* __restrict__ mbf,
                                                   const float* __restrict__ dense_b,
                                                   unsigned short* __restrict__ cbf) {
  __shared__ unsigned short xl[64 * 264];   // 33,792 B: x bf16, row stride 264
  __shared__ float wslds[64 * 17];          // 4,352 B: cols 0-7 w->p, 8-15 s
  const int t = threadIdx.x;
  const int b = blockIdx.x;
  const int wv = t >> 6, l = t & 63;
  const int g = l >> 4, r = l & 15;
  // Stage x: tokens read per-thread (32-thread broadcast), 8 indep uint4 loads
  {
    const uint4* eb4 = (const uint4*)ebf;   // 16 B = 8 bf16; 32 uint4 per row
#pragma unroll
    for (int it = 0; it < 8; ++it) {
      const int idx = it * 256 + t;          // 0..2047
      const int row = idx >> 5, c = idx & 31;
      const int tk = tokens[b * 64 + row];
      *(uint4*)(xl + row * 264 + c * 8) = eb4[(size_t)tk * 32 + c];
    }
  }
  __syncthreads();                          // barrier 1: x staged
  // Phase 1: [W|S] = X[64,256] @ [c|m]^T; A from LDS, B from global (L2-hot)
  {
    const unsigned short* arow = xl + (16 * wv + r) * 264;
    const unsigned short* brow = (r < 8) ? (cbf + (size_t)b * 2048 + r * 256)
                                         : (mbf + (size_t)(r - 8) * 256);
    f32x4 acc = {0.f, 0.f, 0.f, 0.f};
#pragma unroll
    for (int kk = 0; kk < 8; ++kk) {
      const bf16x8 a  = *(const bf16x8*)(arow + kk * 32 + g * 8);
      const bf16x8 bb = *(const bf16x8*)(brow + kk * 32 + g * 8);
      acc = __builtin_amdgcn_mfma_f32_16x16x32_bf16(a, bb, acc, 0, 0, 0);
    }
#pragma unroll
    for (int i = 0; i < 4; ++i)
      wslds[(16 * wv + g * 4 + i) * 17 + r] = acc[i];
  }
  __syncthreads();                          // barrier 2: logits complete
  // Phase 2: per-head softmax over seq (wave w handles heads 2w, 2w+1)
  {
#pragma unroll
    for (int hh = 0; hh < 2; ++hh) {
      const int h = 2 * wv + hh;
      const float v = wslds[l * 17 + h];
      float mx = v;
#pragma unroll
      for (int sft = 32; sft; sft >>= 1) mx = fmaxf(mx, __shfl_xor(mx, sft));
      const float e = expf(v - mx);
      float sm = e;
#pragma unroll
      for (int sft = 32; sft; sft >>= 1) sm += __shfl_xor(sm, sft);
      wslds[l * 17 + h] = e / sm;
    }
  }
  __syncthreads();                          // barrier 3: p complete
  // Phase 3 (every wave, redundant): scores softmax -> coef in registers
  float cc0, cc1;
  {
    float p[8], sv[8];
#pragma unroll
    for (int h = 0; h < 8; ++h) { p[h] = wslds[l*17 + h]; sv[h] = wslds[l*17 + 8 + h]; }
    float sc = dense_b[0];
#pragma unroll
    for (int h = 0; h < 8; ++h) sc += p[h] * sv[h];
    float mx = sc;
#pragma unroll
    for (int sft = 32; sft; sft >>= 1) mx = fmaxf(mx, __shfl_xor(mx, sft));
    const float e = expf(sc - mx);
    float sm = e;
#pragma unroll
    for (int sft = 32; sft; sft >>= 1) sm += __shfl_xor(sm, sft);
    const float attn = e / sm;
    float co[8];
#pragma unroll
    for (int h = 0; h < 8; ++h) co[h] = attn * p[h];
    if      (wv == 0) { cc0 = co[0]; cc1 = co[1]; }
    else if (wv == 1) { cc0 = co[2]; cc1 = co[3]; }
    else if (wv == 2) { cc0 = co[4]; cc1 = co[5]; }
    else              { cc0 = co[6]; cc1 = co[7]; }
  }
  // Phase 4: y by head — wave w owns h=2w,2w+1; lane owns 4 d-cols; x from LDS
  {
    const unsigned int* xu = (const unsigned int*)xl;
    float y0[4] = {}, y1[4] = {};
#pragma unroll
    for (int ll = 0; ll < 64; ++ll) {
      const uint2 xv = *(const uint2*)(xu + ll * 132 + l * 2);
      const float c0 = __shfl(cc0, ll);
      const float c1 = __shfl(cc1, ll);
      const float x0 = ubf(xv.x & 0xffffu);
      const float x1 = ubf(xv.x >> 16);
      const float x2 = ubf(xv.y & 0xffffu);
      const float x3 = ubf(xv.y >> 16);
      y0[0] += c0 * x0; y0[1] += c0 * x1; y0[2] += c0 * x2; y0[3] += c0 * x3;
      y1[0] += c1 * x0; y1[1] += c1 * x1; y1[2] += c1 * x2; y1[3] += c1 * x3;
    }
    uint2 pk0, pk1;
    pk0.x = pack2bf(y0[0], y0[1]); pk0.y = pack2bf(y0[2], y0[3]);
    pk1.x = pack2bf(y1[0], y1[1]); pk1.y = pack2bf(y1[2], y1[3]);
    *(uint2*)(cbf + (size_t)b * 2048 + (2 * wv) * 256 + l * 4)     = pk0;
    *(uint2*)(cbf + (size_t)b * 2048 + (2 * wv + 1) * 256 + l * 4) = pk1;
  }
}

// ---- generic tiled GEMM: C = A@B, row-major, grid.z strides (A optionally bf16)
template <bool A_BF16>
__global__ __launch_bounds__(256) void gemm_t(const void* __restrict__ Av,
                                              const float* __restrict__ Bm,
                                              float* __restrict__ C,
                                              int N, int K, int lda, int ldb, int ldc,
                                              long aZ, long bZ, long cZ) {
  __shared__ float As[64 * 20];
  __shared__ float Bs[16 * 68];
  const int t = threadIdx.x;
  const int bm = blockIdx.x * 64, bn = blockIdx.y * 64;
  Bm += (long)blockIdx.z * bZ;
  C  += (long)blockIdx.z * cZ;
  const int ty = t >> 4, tx = t & 15;
  const int lr = t >> 2, lj = (t & 3) * 4;
  const int lk = t >> 4, ln = (t & 15) * 4;
  float acc[4][4] = {};
  for (int k0 = 0; k0 < K; k0 += 16) {
    float4 a4;
    if constexpr (A_BF16) {
      const unsigned short* A = (const unsigned short*)Av + (long)blockIdx.z * aZ;
      const uint2 au = *(const uint2*)(A + (size_t)(bm + lr) * lda + k0 + lj);
      a4 = make_float4(ubf(au.x & 0xffffu), ubf(au.x >> 16),
                       ubf(au.y & 0xffffu), ubf(au.y >> 16));
    } else {
      const float* A = (const float*)Av + (long)blockIdx.z * aZ;
      a4 = *(const float4*)(A + (size_t)(bm + lr) * lda + k0 + lj);
    }
    float4 b4 = make_float4(0.f, 0.f, 0.f, 0.f);
    if (bn + ln < N) b4 = *(const float4*)(Bm + (size_t)(k0 + lk) * ldb + bn + ln);
    __syncthreads();
    *(float4*)(As + lr * 20 + lj) = a4;
    *(float4*)(Bs + lk * 68 + ln) = b4;
    __syncthreads();
#pragma unroll
    for (int k = 0; k < 16; ++k) {
      const float a0 = As[(4*ty+0)*20 + k];
      const float a1 = As[(4*ty+1)*20 + k];
      const float a2 = As[(4*ty+2)*20 + k];
      const float a3 = As[(4*ty+3)*20 + k];
      const float4 bb = *(const float4*)(Bs + k * 68 + 4 * tx);
      acc[0][0]+=a0*bb.x; acc[0][1]+=a0*bb.y; acc[0][2]+=a0*bb.z; acc[0][3]+=a0*bb.w;
      acc[1][0]+=a1*bb.x; acc[1][1]+=a1*bb.y; acc[1][2]+=a1*bb.z; acc[1][3]+=a1*bb.w;
      acc[2][0]+=a2*bb.x; acc[2][1]+=a2*bb.y; acc[2][2]+=a2*bb.z; acc[2][3]+=a2*bb.w;
      acc[3][0]+=a3*bb.x; acc[3][1]+=a3*bb.y; acc[3][2]+=a3*bb.z; acc[3][3]+=a3*bb.w;
    }
  }
  if (bn + 4 * tx < N) {
#pragma unroll
    for (int i = 0; i < 4; ++i) {
      *(float4*)(C + (size_t)(bm + 4*ty + i) * ldc + bn + 4*tx) =
          make_float4(acc[i][0], acc[i][1], acc[i][2], acc[i][3]);
    }
  }
}

extern "C" void kernel_launch(void* const* d_in, const int* in_sizes, int n_in,
                              void* d_out, int out_size, void* d_ws, size_t ws_size,
                              hipStream_t stream) {
  const int*   tokens = (const int*)d_in[0];
  const float* emb    = (const float*)d_in[1];
  const float* WQ     = (const float*)d_in[2];
  const float* WK     = (const float*)d_in[3];
  const float* WV     = (const float*)d_in[4];
  const float* WO     = (const float*)d_in[5];
  const float* dw     = (const float*)d_in[6];
  const float* db     = (const float*)d_in[7];
  float* out = (float*)d_out;

  // ushort-unit layout
  unsigned short* base = (unsigned short*)d_ws;
  unsigned short* mbf  = base;                           // 2048
  unsigned short* xbf  = base + 2048;                    // 8192*256   (4 MB)
  unsigned short* tkn  = xbf + (size_t)8192 * 256;       // 2048*256   (1 MB)
  unsigned short* cbf  = tkn + (size_t)2048 * 256;       // 8192*2048  (32 MB)
  unsigned short* ebf  = cbf + (size_t)8192 * 2048;      // 50000*256  (25.6 MB)
  float* cbar = (float*)ebf;                             // aliases ebf (dead after main)

  const size_t need_bytes = (size_t)(2048 + 8192*256 + 2048*256 + 8192*2048
                                     + 50000*256) * 2;
  if (ws_size < need_bytes) return;  // deterministic no-op guard

  prep_kernel<<<dim3(1), dim3(256), 0, stream>>>(WV, WO, dw, mbf);
  prep_T<<<dim3(256), dim3(256), 0, stream>>>(WQ, WK, tkn);
  // emb f32 -> ebf bf16 (50000*256)
  ebf_kernel<<<dim3(2048), dim3(256), 0, stream>>>((const float4*)emb, (uint2*)ebf,
                                                   50000 * 64);
  xbar_kernel<<<dim3(8192), dim3(256), 0, stream>>>(tokens, ebf, xbf);
  // c[b][n] for all b,n in one MFMA GEMM
  cgemm<<<dim3(128, 32), dim3(256), 0, stream>>>(xbf, tkn, cbf);
  // main per-sample: logits, softmaxes, y (overwrites c, bf16)
  main_kernel<<<dim3(8192), dim3(256), 0, stream>>>(tokens, ebf, mbf, db, cbf);
  // cbar[b][h*32+n] = sum_e y[b][h][e] * WV[e][h*32+n]   (A = bf16 y)
  gemm_t<true><<<dim3(128, 1, 8), dim3(256), 0, stream>>>(cbf, WV, cbar, 32, 256, 2048, 256, 256, 256l, 32l, 32l);
  // out = cbar @ WO
  gemm_t<false><<<dim3(128, 4, 1), dim3(256), 0, stream>>>(cbar, WO, out, 256, 256, 256, 256, 256, 0l, 0l, 0l);
}